// Round 2
// baseline (604.184 us; speedup 1.0000x reference)
//
#include <hip/hip_runtime.h>
#include <hip/hip_bf16.h>
#include <stdint.h>

#define ZD 128
#define SD 512
#define MROWS (SD*SD)   // 262144 rows

typedef __attribute__((ext_vector_type(8))) short short8;
typedef __attribute__((ext_vector_type(4))) float floatx4;
typedef __attribute__((ext_vector_type(4))) unsigned short ushort4v;

__device__ __forceinline__ unsigned short f2bf(float f) {
  union { float f; unsigned u; } c; c.f = f;
  unsigned r = c.u + 0x7FFFu + ((c.u >> 16) & 1u);   // RNE
  return (unsigned short)(r >> 16);
}
__device__ __forceinline__ float bf2f(unsigned short h) {
  union { unsigned u; float f; } c; c.u = (unsigned)h << 16;
  return c.f;
}
__device__ __forceinline__ float sigm(float x) { return 1.0f / (1.0f + __expf(-x)); }

// swizzled LDS byte offset for 256B rows: row*256 + (colbyte ^ ((row&7)<<4))
#define SWZ(r, cb) (((r) << 8) + ((cb) ^ (((r) & 7) << 4)))

// ---------------------------------------------------------------- prep: bf16+transpose weights
__global__ __launch_bounds__(256) void prep_weights(
    const float* __restrict__ l1, const float* __restrict__ l2,
    const float* __restrict__ r1, const float* __restrict__ r2,
    const float* __restrict__ gw, const float* __restrict__ ow,
    unsigned short* __restrict__ dst) {
  const float* srcs[6] = {l1, l2, r1, r2, gw, ow};
  const float* s = srcs[blockIdx.x];
  unsigned short* d = dst + (size_t)blockIdx.x * ZD * ZD;
  for (int i = threadIdx.x; i < ZD * ZD; i += blockDim.x) {
    int k = i >> 7, n = i & 127;
    d[n * ZD + k] = f2bf(s[i]);     // WT[n][k] = W[k][n]
  }
}

// ---------------------------------------------------------------- LN over Z, f32 -> bf16 x
__global__ __launch_bounds__(256) void ln_kernel(
    const float* __restrict__ in, const float* __restrict__ w,
    const float* __restrict__ b, unsigned short* __restrict__ xo) {
  const int tid = threadIdx.x;
  const int lane = tid & 63;
  const int row = blockIdx.x * 4 + (tid >> 6);
  float2 v = reinterpret_cast<const float2*>(in)[(size_t)row * 64 + lane];
  float s = v.x + v.y, q = v.x * v.x + v.y * v.y;
  #pragma unroll
  for (int m = 1; m < 64; m <<= 1) { s += __shfl_xor(s, m); q += __shfl_xor(q, m); }
  float mu = s * (1.0f / ZD);
  float var = q * (1.0f / ZD) - mu * mu;
  float rstd = rsqrtf(var + 1e-5f);
  float2 wv = reinterpret_cast<const float2*>(w)[lane];
  float2 bv = reinterpret_cast<const float2*>(b)[lane];
  unsigned o0 = f2bf((v.x - mu) * rstd * wv.x + bv.x);
  unsigned o1 = f2bf((v.y - mu) * rstd * wv.y + bv.y);
  reinterpret_cast<unsigned*>(xo)[(size_t)row * 64 + lane] = o0 | (o1 << 16);
}

// ---------------------------------------------------------------- projections (left/right/gate)
// job = blockIdx.y: 0 -> leftT = sig(x@l1)*(x@l2); 1 -> rightT; 2 -> gateT = sig(x@gw)
// outputs channel-major: out[e][m], m = flattened row
__global__ __launch_bounds__(256) void proj_kernel(
    const unsigned short* __restrict__ x,    // [M][128] bf16
    const unsigned short* __restrict__ wT,   // 6 x [128][128] bf16 (pre-transposed [n][k])
    unsigned short* __restrict__ leftT,
    unsigned short* __restrict__ rightT,
    unsigned short* __restrict__ gateT) {
  __shared__ char xs[32 * 1024];
  __shared__ char w1s[32 * 1024];
  __shared__ char w2s[32 * 1024];
  const int tid = threadIdx.x;
  const int job = blockIdx.y;
  const int m0 = blockIdx.x * 128;

  #pragma unroll
  for (int i = 0; i < 8; ++i) {
    int c = i * 256 + tid;
    int r = c >> 4, cb = (c & 15) << 4;
    *reinterpret_cast<short8*>(xs + SWZ(r, cb)) =
      *reinterpret_cast<const short8*>(x + (size_t)(m0 + r) * ZD + (cb >> 1));
  }
  const unsigned short* wsrc = wT + (size_t)(job == 0 ? 0 : job == 1 ? 2 : 4) * ZD * ZD;
  #pragma unroll
  for (int i = 0; i < 8; ++i) {
    int c = i * 256 + tid;
    int r = c >> 4, cb = (c & 15) << 4;
    *reinterpret_cast<short8*>(w1s + SWZ(r, cb)) =
      *reinterpret_cast<const short8*>(wsrc + r * ZD + (cb >> 1));
  }
  if (job < 2) {
    const unsigned short* w2p = wsrc + ZD * ZD;
    #pragma unroll
    for (int i = 0; i < 8; ++i) {
      int c = i * 256 + tid;
      int r = c >> 4, cb = (c & 15) << 4;
      *reinterpret_cast<short8*>(w2s + SWZ(r, cb)) =
        *reinterpret_cast<const short8*>(w2p + r * ZD + (cb >> 1));
    }
  }
  __syncthreads();

  const int wid = tid >> 6, lane = tid & 63;
  const int msub = (wid >> 1) * 64, esub = (wid & 1) * 64;
  const int fr = lane & 15, fq = lane >> 4;
  const bool two = (job < 2);
  floatx4 acc1[4][4] = {};
  floatx4 acc2[4][4] = {};
  #pragma unroll
  for (int ks = 0; ks < 4; ++ks) {
    const int kb = ks * 64 + fq * 16;
    short8 a[4], b1[4], b2[4];
    #pragma unroll
    for (int i = 0; i < 4; ++i)
      a[i] = *reinterpret_cast<const short8*>(xs + SWZ(msub + i * 16 + fr, kb));
    #pragma unroll
    for (int j = 0; j < 4; ++j) {
      b1[j] = *reinterpret_cast<const short8*>(w1s + SWZ(esub + j * 16 + fr, kb));
      b2[j] = two ? *reinterpret_cast<const short8*>(w2s + SWZ(esub + j * 16 + fr, kb)) : b1[j];
    }
    #pragma unroll
    for (int i = 0; i < 4; ++i)
      #pragma unroll
      for (int j = 0; j < 4; ++j) {
        acc1[i][j] = __builtin_amdgcn_mfma_f32_16x16x32_bf16(a[i], b1[j], acc1[i][j], 0, 0, 0);
        if (two)
          acc2[i][j] = __builtin_amdgcn_mfma_f32_16x16x32_bf16(a[i], b2[j], acc2[i][j], 0, 0, 0);
      }
  }
  unsigned short* dst = (job == 0) ? leftT : (job == 1) ? rightT : gateT;
  #pragma unroll
  for (int i = 0; i < 4; ++i) {
    const int mrow = m0 + msub + i * 16 + fq * 4;     // 4 reg-consecutive rows
    #pragma unroll
    for (int j = 0; j < 4; ++j) {
      const int e = esub + j * 16 + fr;
      ushort4v pkt;
      #pragma unroll
      for (int r = 0; r < 4; ++r) {
        float v = two ? sigm(acc1[i][j][r]) * acc2[i][j][r] : sigm(acc1[i][j][r]);
        pkt[r] = f2bf(v);
      }
      *reinterpret_cast<ushort4v*>(dst + (size_t)e * MROWS + mrow) = pkt;
    }
  }
}

// ---------------------------------------------------------------- einsum: per-channel GEMM-BT
// D[t,s] = sum_r rightT[e][t][r] * leftT[e][s][r]  -> pT[e][s][t]
__global__ __launch_bounds__(256) void einsum_kernel(
    const unsigned short* __restrict__ leftT,
    const unsigned short* __restrict__ rightT,
    unsigned short* __restrict__ pT) {
  __shared__ char at[32 * 1024];
  __shared__ char bt[32 * 1024];
  const int tid = threadIdx.x;
  const int e = blockIdx.z;
  const int t0 = blockIdx.x * 128, s0 = blockIdx.y * 128;
  const unsigned short* Ag = rightT + (size_t)e * MROWS;   // [512][512] rows = t
  const unsigned short* Bg = leftT  + (size_t)e * MROWS;   // rows = s
  const int wid = tid >> 6, lane = tid & 63;
  const int tsub = (wid >> 1) * 64, ssub = (wid & 1) * 64;
  const int fr = lane & 15, fq = lane >> 4;
  floatx4 acc[4][4] = {};
  for (int ko = 0; ko < 4; ++ko) {       // K = 512 in 4 x 128 steps
    __syncthreads();
    #pragma unroll
    for (int i = 0; i < 8; ++i) {
      int c = i * 256 + tid;
      int r = c >> 4, cb = (c & 15) << 4;
      *reinterpret_cast<short8*>(at + SWZ(r, cb)) =
        *reinterpret_cast<const short8*>(Ag + (size_t)(t0 + r) * SD + ko * 128 + (cb >> 1));
      *reinterpret_cast<short8*>(bt + SWZ(r, cb)) =
        *reinterpret_cast<const short8*>(Bg + (size_t)(s0 + r) * SD + ko * 128 + (cb >> 1));
    }
    __syncthreads();
    #pragma unroll
    for (int kk = 0; kk < 4; ++kk) {
      const int kb = kk * 64 + fq * 16;
      short8 a[4], b[4];
      #pragma unroll
      for (int i = 0; i < 4; ++i)
        a[i] = *reinterpret_cast<const short8*>(at + SWZ(tsub + i * 16 + fr, kb));
      #pragma unroll
      for (int j = 0; j < 4; ++j)
        b[j] = *reinterpret_cast<const short8*>(bt + SWZ(ssub + j * 16 + fr, kb));
      #pragma unroll
      for (int i = 0; i < 4; ++i)
        #pragma unroll
        for (int j = 0; j < 4; ++j)
          acc[i][j] = __builtin_amdgcn_mfma_f32_16x16x32_bf16(a[i], b[j], acc[i][j], 0, 0, 0);
    }
  }
  unsigned short* Pg = pT + (size_t)e * MROWS;
  #pragma unroll
  for (int i = 0; i < 4; ++i) {
    const int tt = t0 + tsub + i * 16 + fq * 4;       // 4 reg-consecutive t
    #pragma unroll
    for (int j = 0; j < 4; ++j) {
      const int ss = s0 + ssub + j * 16 + fr;
      ushort4v pkt;
      #pragma unroll
      for (int r = 0; r < 4; ++r) pkt[r] = f2bf(acc[i][j][r]);
      *reinterpret_cast<ushort4v*>(Pg + (size_t)ss * SD + tt) = pkt;
    }
  }
}

// ---------------------------------------------------------------- final: LN(E) + @out_w * gate + residual
__global__ __launch_bounds__(256) void final_kernel(
    const unsigned short* __restrict__ pT,     // [128][M]
    const unsigned short* __restrict__ gateT,  // [128][M]
    const unsigned short* __restrict__ owT,    // [z][e] bf16
    const float* __restrict__ nw, const float* __restrict__ nb,
    const float* __restrict__ resid, float* __restrict__ out) {
  __shared__ char Pl[128 * 256];   // [e][t] bf16 plain
  __shared__ char Pn[128 * 256];   // [t][e] bf16 swizzled
  __shared__ char Gl[128 * 272];   // [z][t] bf16 padded
  __shared__ float red[512];
  __shared__ float mu_s[128], rs_s[128], nw_s[128], nb_s[128];
  const int tid = threadIdx.x;
  const int m0 = blockIdx.x * 128;
  #pragma unroll
  for (int i = 0; i < 8; ++i) {
    int c = i * 256 + tid;
    int r = c >> 4, cb = (c & 15) << 4;
    *reinterpret_cast<short8*>(Pl + r * 256 + cb) =
      *reinterpret_cast<const short8*>(pT + (size_t)r * MROWS + m0 + (cb >> 1));
    *reinterpret_cast<short8*>(Gl + r * 272 + cb) =
      *reinterpret_cast<const short8*>(gateT + (size_t)r * MROWS + m0 + (cb >> 1));
  }
  if (tid < 128) { nw_s[tid] = nw[tid]; nb_s[tid] = nb[tid]; }
  __syncthreads();
  const int t = tid & 127, h = tid >> 7;
  const unsigned short* colp = reinterpret_cast<const unsigned short*>(Pl) + t;
  {
    float s = 0.f, q = 0.f;
    for (int e2 = 0; e2 < 64; ++e2) {
      float v = bf2f(colp[(h * 64 + e2) * 128]);
      s += v; q += v * v;
    }
    red[h * 128 + t] = s;
    red[256 + h * 128 + t] = q;
  }
  __syncthreads();
  if (tid < 128) {
    float ss = red[tid] + red[128 + tid];
    float qq = red[256 + tid] + red[384 + tid];
    float mu = ss * (1.f / 128.f);
    float var = qq * (1.f / 128.f) - mu * mu;
    mu_s[tid] = mu;
    rs_s[tid] = rsqrtf(var + 1e-5f);
  }
  __syncthreads();
  {
    float mu = mu_s[t], rs = rs_s[t];
    for (int e2 = 0; e2 < 64; ++e2) {
      int e = h * 64 + e2;
      float v = (bf2f(colp[e * 128]) - mu) * rs * nw_s[e] + nb_s[e];
      *reinterpret_cast<unsigned short*>(Pn + (t << 8) + ((e * 2) ^ ((t & 7) << 4))) = f2bf(v);
    }
  }
  __syncthreads();
  const int wid = tid >> 6, lane = tid & 63;
  const int zsub = (wid >> 1) * 64, tsub = (wid & 1) * 64;
  const int fr = lane & 15, fq = lane >> 4;
  floatx4 acc[4][4] = {};
  #pragma unroll
  for (int ks = 0; ks < 4; ++ks) {
    short8 a[4], b[4];
    #pragma unroll
    for (int i = 0; i < 4; ++i)
      a[i] = *reinterpret_cast<const short8*>(owT + (size_t)(zsub + i * 16 + fr) * ZD + ks * 32 + fq * 8);
    #pragma unroll
    for (int j = 0; j < 4; ++j)
      b[j] = *reinterpret_cast<const short8*>(Pn + SWZ(tsub + j * 16 + fr, ks * 64 + fq * 16));
    #pragma unroll
    for (int i = 0; i < 4; ++i)
      #pragma unroll
      for (int j = 0; j < 4; ++j)
        acc[i][j] = __builtin_amdgcn_mfma_f32_16x16x32_bf16(a[i], b[j], acc[i][j], 0, 0, 0);
  }
  #pragma unroll
  for (int j = 0; j < 4; ++j) {
    const int tt = tsub + j * 16 + fr;
    #pragma unroll
    for (int i = 0; i < 4; ++i) {
      const int zb = zsub + i * 16 + fq * 4;          // 4 reg-consecutive z
      const float4 res = *reinterpret_cast<const float4*>(resid + (size_t)(m0 + tt) * ZD + zb);
      float g0 = bf2f(*reinterpret_cast<const unsigned short*>(Gl + (zb + 0) * 272 + tt * 2));
      float g1 = bf2f(*reinterpret_cast<const unsigned short*>(Gl + (zb + 1) * 272 + tt * 2));
      float g2 = bf2f(*reinterpret_cast<const unsigned short*>(Gl + (zb + 2) * 272 + tt * 2));
      float g3 = bf2f(*reinterpret_cast<const unsigned short*>(Gl + (zb + 3) * 272 + tt * 2));
      float4 o;
      o.x = res.x + acc[i][j][0] * g0;
      o.y = res.y + acc[i][j][1] * g1;
      o.z = res.z + acc[i][j][2] * g2;
      o.w = res.w + acc[i][j][3] * g3;
      *reinterpret_cast<float4*>(out + (size_t)(m0 + tt) * ZD + zb) = o;
    }
  }
}

// ----------------------------------------------------------------
extern "C" void kernel_launch(void* const* d_in, const int* in_sizes, int n_in,
                              void* d_out, int out_size, void* d_ws, size_t ws_size,
                              hipStream_t stream) {
  const float* pair = (const float*)d_in[0];
  const float* ln_w = (const float*)d_in[1];
  const float* ln_b = (const float*)d_in[2];
  const float* l1   = (const float*)d_in[3];
  const float* l2   = (const float*)d_in[4];
  const float* r1   = (const float*)d_in[5];
  const float* r2   = (const float*)d_in[6];
  const float* nw   = (const float*)d_in[7];
  const float* nb   = (const float*)d_in[8];
  const float* ow   = (const float*)d_in[9];
  const float* gw   = (const float*)d_in[10];
  float* out = (float*)d_out;

  // workspace layout (bf16 elements):
  //   [0, 33554432)        x   (aliased later by pT)
  //   [33554432, 67108864) gateT
  //   [67108864, +6*16384) transposed bf16 weights {l1T,l2T,r1T,r2T,gwT,owT}
  unsigned short* xws   = reinterpret_cast<unsigned short*>(d_ws);
  unsigned short* gateT = xws + (size_t)MROWS * ZD;
  unsigned short* wT    = gateT + (size_t)MROWS * ZD;
  unsigned short* owT   = wT + (size_t)5 * ZD * ZD;
  // leftT/rightT live in d_out (dead before final_kernel writes it)
  unsigned short* leftT  = reinterpret_cast<unsigned short*>(d_out);
  unsigned short* rightT = leftT + (size_t)MROWS * ZD;
  unsigned short* pTbuf  = xws;   // alias x (x dead after proj_kernel)

  prep_weights<<<6, 256, 0, stream>>>(l1, l2, r1, r2, gw, ow, wT);
  ln_kernel<<<MROWS / 4, 256, 0, stream>>>(pair, ln_w, ln_b, xws);
  proj_kernel<<<dim3(2048, 3), 256, 0, stream>>>(xws, wT, leftT, rightT, gateT);
  einsum_kernel<<<dim3(4, 4, 128), 256, 0, stream>>>(leftT, rightT, pTbuf);
  final_kernel<<<2048, 256, 0, stream>>>(pTbuf, gateT, owT, nw, nb, pair, out);
}